// Round 1
// baseline (2860.078 us; speedup 1.0000x reference)
//
#include <hip/hip_runtime.h>
#include <hip/hip_bf16.h>

typedef unsigned int u32;
typedef unsigned long long u64;

#define H_FM 100
#define W_FM 150
#define CIN 1024
#define CMID 512
#define NPIX 15000          // H_FM * W_FM
#define NANCH 135000        // NPIX * 9
#define KTOT 9216           // 9 * CIN
#define PRE_NMS_N 6000
#define POST_NMS_N 300
#define WPR 94              // ceil(6000/64) words per mask row

__device__ __forceinline__ u32 fkey(float f) {
  u32 u = __float_as_uint(f);
  return (u & 0x80000000u) ? ~u : (u | 0x80000000u);
}

__device__ __forceinline__ u64 shfl64(u64 v, int src) {
  u32 lo = (u32)__shfl((int)(u32)v, src, 64);
  u32 hi = (u32)__shfl((int)(u32)(v >> 32), src, 64);
  return ((u64)hi << 32) | (u64)lo;
}

// ---------------------------------------------------------------------------
// Kernel 1: 3x3 conv (SAME, NHWC, HWIO) + bias + ReLU as implicit GEMM.
// M=15000 pixels, N=512, K=9216. Tile 128x128, BK=16, 256 thr, 8x8 micro.
// ---------------------------------------------------------------------------
__global__ __launch_bounds__(256) void k_conv(
    const float* __restrict__ fm, const float* __restrict__ Wr,
    const float* __restrict__ br, float* __restrict__ rpn)
{
  __shared__ float As[16][132];   // [k][m], padded (2-way bank alias = free)
  __shared__ float Bs[16][128];   // [k][n]

  const int tid = threadIdx.x;
  const int ntile = blockIdx.x & 3;     // 4 n-tiles of 128
  const int mtile = blockIdx.x >> 2;    // 118 m-tiles of 128
  const int bm = mtile * 128, bn = ntile * 128;

  // A-load mapping: thread loads float4 along k for two rows
  const int a_kg = tid & 3;             // k-group (float4): k = a_kg*4..+3
  const int a_r  = tid >> 2;            // rows a_r and a_r+64
  const int m0 = bm + a_r, m1 = m0 + 64;
  const int y0 = m0 / W_FM, x0 = m0 % W_FM;
  const int y1 = m1 / W_FM, x1 = m1 % W_FM;
  const bool mv0 = m0 < NPIX, mv1 = m1 < NPIX;

  // B-load mapping
  const int b_n4 = (tid & 31) << 2;     // n offset (float4)
  const int b_k  = tid >> 5;            // k rows b_k, b_k+8

  const int tc = tid & 15, tr = tid >> 4;

  float acc[8][8];
  #pragma unroll
  for (int i = 0; i < 8; ++i)
    #pragma unroll
    for (int j = 0; j < 8; ++j) acc[i][j] = 0.f;

  const float4 z4 = make_float4(0.f, 0.f, 0.f, 0.f);

  for (int seg = 0; seg < 9; ++seg) {
    const int dy = seg / 3 - 1, dx = seg % 3 - 1;
    const int iy0 = y0 + dy, ix0 = x0 + dx;
    const int iy1 = y1 + dy, ix1 = x1 + dx;
    const bool v0 = mv0 && (unsigned)iy0 < H_FM && (unsigned)ix0 < W_FM;
    const bool v1 = mv1 && (unsigned)iy1 < H_FM && (unsigned)ix1 < W_FM;
    const float* pa0 = fm + (((iy0 * W_FM + ix0) << 10) + (a_kg << 2));
    const float* pa1 = fm + (((iy1 * W_FM + ix1) << 10) + (a_kg << 2));
    const float* pb  = Wr + ((size_t)(seg * CIN) * CMID) + bn + b_n4;

    for (int kc = 0; kc < CIN; kc += 16) {
      float4 av0 = v0 ? *(const float4*)(pa0 + kc) : z4;
      float4 av1 = v1 ? *(const float4*)(pa1 + kc) : z4;
      float4 bv0 = *(const float4*)(pb + (size_t)(kc + b_k) * CMID);
      float4 bv1 = *(const float4*)(pb + (size_t)(kc + b_k + 8) * CMID);

      __syncthreads();
      const int ka = a_kg << 2;
      As[ka + 0][a_r] = av0.x; As[ka + 1][a_r] = av0.y;
      As[ka + 2][a_r] = av0.z; As[ka + 3][a_r] = av0.w;
      As[ka + 0][a_r + 64] = av1.x; As[ka + 1][a_r + 64] = av1.y;
      As[ka + 2][a_r + 64] = av1.z; As[ka + 3][a_r + 64] = av1.w;
      *(float4*)&Bs[b_k][b_n4]     = bv0;
      *(float4*)&Bs[b_k + 8][b_n4] = bv1;
      __syncthreads();

      #pragma unroll
      for (int kk = 0; kk < 16; ++kk) {
        float a8[8], b8[8];
        *(float4*)&a8[0] = *(const float4*)&As[kk][tr * 8];
        *(float4*)&a8[4] = *(const float4*)&As[kk][tr * 8 + 4];
        *(float4*)&b8[0] = *(const float4*)&Bs[kk][tc * 8];
        *(float4*)&b8[4] = *(const float4*)&Bs[kk][tc * 8 + 4];
        #pragma unroll
        for (int i = 0; i < 8; ++i)
          #pragma unroll
          for (int j = 0; j < 8; ++j)
            acc[i][j] = fmaf(a8[i], b8[j], acc[i][j]);
      }
    }
  }

  // epilogue: bias + relu + store
  float4 bias0 = *(const float4*)(br + bn + tc * 8);
  float4 bias1 = *(const float4*)(br + bn + tc * 8 + 4);
  #pragma unroll
  for (int i = 0; i < 8; ++i) {
    int m = bm + tr * 8 + i;
    if (m < NPIX) {
      float* op = rpn + (size_t)m * CMID + bn + tc * 8;
      float4 o0, o1;
      o0.x = fmaxf(acc[i][0] + bias0.x, 0.f);
      o0.y = fmaxf(acc[i][1] + bias0.y, 0.f);
      o0.z = fmaxf(acc[i][2] + bias0.z, 0.f);
      o0.w = fmaxf(acc[i][3] + bias0.w, 0.f);
      o1.x = fmaxf(acc[i][4] + bias1.x, 0.f);
      o1.y = fmaxf(acc[i][5] + bias1.y, 0.f);
      o1.z = fmaxf(acc[i][6] + bias1.z, 0.f);
      o1.w = fmaxf(acc[i][7] + bias1.w, 0.f);
      *(float4*)op = o0;
      *(float4*)(op + 4) = o1;
    }
  }
}

// ---------------------------------------------------------------------------
// Kernel 2: 1x1 heads + softmax + anchor decode + clip + min-size filter.
// One wave per pixel.
// ---------------------------------------------------------------------------
__global__ __launch_bounds__(64) void k_heads(
    const float* __restrict__ rpn,
    const float* __restrict__ Ws, const float* __restrict__ bs,
    const float* __restrict__ Wb, const float* __restrict__ bb,
    const int* __restrict__ img,
    float* __restrict__ fg, float4* __restrict__ boxes)
{
  __shared__ float r[512];
  __shared__ float vals[54];
  const int p = blockIdx.x, lane = threadIdx.x;
  const float* rp = rpn + (size_t)p * CMID;
  *(float4*)&r[lane * 8]     = *(const float4*)(rp + lane * 8);
  *(float4*)&r[lane * 8 + 4] = *(const float4*)(rp + lane * 8 + 4);
  __syncthreads();

  if (lane < 54) {
    const float* wp;
    int stride;
    float acc;
    if (lane < 18) { wp = Ws + lane; stride = 18; acc = bs[lane]; }
    else           { wp = Wb + (lane - 18); stride = 36; acc = bb[lane - 18]; }
    #pragma unroll 8
    for (int c = 0; c < 512; ++c) acc = fmaf(r[c], wp[c * stride], acc);
    vals[lane] = acc;
  }
  __syncthreads();

  if (lane < 9) {
    const int a = lane;
    // anchor refs (py-faster-rcnn, base 16, ratios .5/1/2, scales 8/16/32)
    const float AW[9] = {184.f, 368.f, 736.f, 128.f, 256.f, 512.f,  88.f, 176.f, 352.f};
    const float AH[9] = { 96.f, 192.f, 384.f, 128.f, 256.f, 512.f, 176.f, 352.f, 704.f};
    const int y = p / W_FM, x = p % W_FM;

    float c0 = vals[2 * a], c1 = vals[2 * a + 1];
    float score = 1.f / (1.f + expf(c0 - c1));

    float dxv = vals[18 + 4 * a + 0];
    float dyv = vals[18 + 4 * a + 1];
    float dwv = vals[18 + 4 * a + 2];
    float dhv = vals[18 + 4 * a + 3];

    float aw = AW[a], ah = AH[a];
    float acx = (float)(x * 16 + 8);  // x1 + 0.5*aw == cx + 0.5 == 8 for all refs
    float acy = (float)(y * 16 + 8);
    float pcx = dxv * aw + acx;
    float pcy = dyv * ah + acy;
    float pw = expf(dwv) * aw;
    float ph = expf(dhv) * ah;

    float imh1 = (float)img[0] - 1.f;
    float imw1 = (float)img[1] - 1.f;
    float b0 = fminf(fmaxf(pcx - 0.5f * pw, 0.f), imw1);
    float b1 = fminf(fmaxf(pcy - 0.5f * ph, 0.f), imh1);
    float b2 = fminf(fmaxf(pcx + 0.5f * pw, 0.f), imw1);
    float b3 = fminf(fmaxf(pcy + 0.5f * ph, 0.f), imh1);

    float bw = b2 - b0 + 1.f, bh = b3 - b1 + 1.f;
    if (!(bw >= 16.f && bh >= 16.f)) score = -1e9f;

    int gi = p * 9 + a;
    fg[gi] = score;
    boxes[gi] = make_float4(b0, b1, b2, b3);
  }
}

// ---------------------------------------------------------------------------
// Radix-select (exact top-6000 threshold) machinery.
// ctl[0]=prefix/threshold, ctl[1]=kneed, ctl[2]=cntA, ctl[3]=cntB
// ---------------------------------------------------------------------------
__global__ void k_init(u32* __restrict__ hist, u32* __restrict__ ctl) {
  hist[threadIdx.x] = 0;
  if (threadIdx.x == 0) { ctl[0] = 0; ctl[1] = PRE_NMS_N; ctl[2] = 0; ctl[3] = 0; }
}

__global__ __launch_bounds__(256) void k_hist(
    const float* __restrict__ fg, u32* __restrict__ hist,
    const u32* __restrict__ ctl, int pass)
{
  __shared__ u32 h[256];
  h[threadIdx.x] = 0;
  __syncthreads();
  const int shift = 24 - 8 * pass;
  const u32 prefix = ctl[0];
  for (int i = blockIdx.x * 256 + threadIdx.x; i < NANCH; i += 128 * 256) {
    u32 key = fkey(fg[i]);
    bool match = (pass == 0) || ((key >> (shift + 8)) == prefix);
    if (match) atomicAdd(&h[(key >> shift) & 255], 1u);
  }
  __syncthreads();
  u32 c = h[threadIdx.x];
  if (c) atomicAdd(&hist[threadIdx.x], c);
}

__global__ void k_scan(u32* __restrict__ hist, u32* __restrict__ ctl) {
  if (threadIdx.x == 0) {
    u32 kneed = ctl[1];
    u32 cum = 0;
    int d = 0;
    for (int dd = 255; dd >= 0; --dd) {
      u32 c = hist[dd];
      if (cum + c >= kneed) { d = dd; break; }
      cum += c;
    }
    ctl[0] = (ctl[0] << 8) | (u32)d;
    ctl[1] = kneed - cum;
  }
  __syncthreads();
  hist[threadIdx.x] = 0;   // ready for next pass
}

__global__ __launch_bounds__(256) void k_compact(
    const float* __restrict__ fg, u32* __restrict__ ctl,
    u64* __restrict__ listA, u32* __restrict__ listB)
{
  int i = blockIdx.x * 256 + threadIdx.x;
  if (i >= NANCH) return;
  u32 T = ctl[0];
  u32 key = fkey(fg[i]);
  if (key > T) {
    u32 slot = atomicAdd(&ctl[2], 1u);
    listA[slot] = ((u64)key << 32) | (u64)(0xFFFFFFFFu - (u32)i);
  } else if (key == T) {
    u32 slot = atomicAdd(&ctl[3], 1u);
    if (slot < 8192) listB[slot] = (u32)i;
  }
}

// take the kneed smallest indices among the ==T ties (lax.top_k tiebreak)
__global__ __launch_bounds__(256) void k_tiefix(
    u32* __restrict__ ctl, const u32* __restrict__ listB, u64* __restrict__ listA)
{
  __shared__ u32 s[8192];
  const int tid = threadIdx.x;
  const u32 kneed = ctl[1];
  const u32 base = ctl[2];
  const u32 cntB = min(ctl[3], 8192u);
  const u32 T = ctl[0];
  if (kneed == 0) return;
  if (cntB == kneed) {
    for (u32 t = tid; t < kneed; t += 256)
      listA[base + t] = ((u64)T << 32) | (u64)(0xFFFFFFFFu - listB[t]);
    return;
  }
  u32 n2 = 1;
  while (n2 < cntB) n2 <<= 1;
  for (u32 i = tid; i < n2; i += 256) s[i] = (i < cntB) ? listB[i] : 0xFFFFFFFFu;
  __syncthreads();
  for (u32 k = 2; k <= n2; k <<= 1) {
    for (u32 j = k >> 1; j > 0; j >>= 1) {
      for (u32 i = tid; i < n2; i += 256) {
        u32 ixj = i ^ j;
        if (ixj > i) {
          u32 a = s[i], b = s[ixj];
          bool up = ((i & k) == 0);
          if ((a > b) == up) { s[i] = b; s[ixj] = a; }   // ascending
        }
      }
      __syncthreads();
    }
  }
  for (u32 t = tid; t < kneed; t += 256)
    listA[base + t] = ((u64)T << 32) | (u64)(0xFFFFFFFFu - s[t]);
}

// full bitonic sort of the 6000 selected (desc key, asc idx via packed ~idx)
__global__ __launch_bounds__(1024) void k_sort(
    const u64* __restrict__ listA, u64* __restrict__ sorted)
{
  __shared__ u64 s[8192];
  const int tid = threadIdx.x;
  for (int i = tid; i < 8192; i += 1024) s[i] = (i < PRE_NMS_N) ? listA[i] : 0ull;
  __syncthreads();
  for (int k = 2; k <= 8192; k <<= 1) {
    for (int j = k >> 1; j > 0; j >>= 1) {
      for (int i = tid; i < 8192; i += 1024) {
        int ixj = i ^ j;
        if (ixj > i) {
          u64 a = s[i], b = s[ixj];
          bool up = ((i & k) == 0);
          if ((a < b) == up) { s[i] = b; s[ixj] = a; }   // descending
        }
      }
      __syncthreads();
    }
  }
  for (int i = tid; i < 8192; i += 1024) sorted[i] = s[i];
}

__global__ __launch_bounds__(256) void k_gather(
    const u64* __restrict__ sorted, const float4* __restrict__ boxes,
    float4* __restrict__ tb)
{
  int t = blockIdx.x * 256 + threadIdx.x;
  if (t >= PRE_NMS_N) return;
  u64 p = sorted[t];
  u32 idx = 0xFFFFFFFFu - (u32)(p & 0xFFFFFFFFull);
  tb[t] = boxes[idx];
}

// suppression bitmask: mask[i][w] bit b == (IoU(i, w*64+b) > 0.7 && j > i)
__global__ __launch_bounds__(64) void k_mask(
    const float4* __restrict__ tb, u64* __restrict__ mask)
{
  __shared__ float4 cb[64];
  const int bj = blockIdx.x, bi = blockIdx.y, t = threadIdx.x;
  const int j0 = bj * 64;
  const int jn = min(64, PRE_NMS_N - j0);
  if (t < jn) cb[t] = tb[j0 + t];
  __syncthreads();
  const int i = bi * 64 + t;
  if (i >= PRE_NMS_N) return;
  const float4 b = tb[i];
  const float ai = (b.z - b.x + 1.f) * (b.w - b.y + 1.f);
  u64 bits = 0;
  for (int tt = 0; tt < jn; ++tt) {
    int j = j0 + tt;
    if (j <= i) continue;
    float4 c = cb[tt];
    float iw = fminf(b.z, c.z) - fmaxf(b.x, c.x) + 1.f;
    float ih = fminf(b.w, c.w) - fmaxf(b.y, c.y) + 1.f;
    float inter = fmaxf(iw, 0.f) * fmaxf(ih, 0.f);
    float aj = (c.z - c.x + 1.f) * (c.w - c.y + 1.f);
    float iou = inter / (ai + aj - inter);
    if (iou > 0.7f) bits |= (1ull << tt);
  }
  mask[(size_t)i * WPR + bj] = bits;
}

// single-wave greedy NMS walk with register-resident removed-bitmask;
// early exit after 300 kept (only the first 300 kept reach the output)
__global__ __launch_bounds__(64) void k_nms(
    const u64* __restrict__ mask, const float* __restrict__ tb,
    const u64* __restrict__ sorted, float* __restrict__ out)
{
  const int lane = threadIdx.x;
  u64 r0 = 0, r1 = 0;   // removed words: lane -> word lane; lane -> word 64+lane
  int kept = 0;
  const u32 kcut = fkey(-1e8f);
  for (int i = 0; i < PRE_NMS_N; ++i) {
    const int w = i >> 6, b = i & 63;
    u64 v0 = shfl64(r0, w & 63);
    u64 v1 = shfl64(r1, w & 63);
    u64 word = (w < 64) ? v0 : v1;
    if (!((word >> b) & 1ull)) {
      u32 key = (u32)(sorted[i] >> 32);
      if (key <= kcut) break;          // sorted tail: all filtered -> zeros
      if (lane < 4) out[kept * 4 + lane] = tb[i * 4 + lane];
      ++kept;
      if (kept >= POST_NMS_N) break;
      const u64* row = mask + (size_t)i * WPR;
      r0 |= row[lane];
      if (lane < WPR - 64) r1 |= row[64 + lane];
    }
  }
  for (int j = kept * 4 + lane; j < POST_NMS_N * 4; j += 64) out[j] = 0.f;
}

// ---------------------------------------------------------------------------
extern "C" void kernel_launch(void* const* d_in, const int* in_sizes, int n_in,
                              void* d_out, int out_size, void* d_ws, size_t ws_size,
                              hipStream_t stream) {
  const float* fm  = (const float*)d_in[0];
  const float* Wr  = (const float*)d_in[1];
  const float* br  = (const float*)d_in[2];
  const float* Wsc = (const float*)d_in[3];
  const float* bsc = (const float*)d_in[4];
  const float* Wbb = (const float*)d_in[5];
  const float* bbb = (const float*)d_in[6];
  const int*   img = (const int*)d_in[7];
  float* out = (float*)d_out;

  char* w = (char*)d_ws;
  size_t off = 0;
  float* rpn = (float*)(w + off);      off += (size_t)NPIX * CMID * 4;   // 30,720,000
  float* fg = (float*)(w + off);       off += (size_t)NANCH * 4;         //    540,000
  float4* boxes = (float4*)(w + off);  off += (size_t)NANCH * 16;        //  2,160,000
  u32* hist = (u32*)(w + off);         off += 1024;
  u32* ctl = (u32*)(w + off);          off += 64;
  u64* listA = (u64*)(w + off);        off += (size_t)PRE_NMS_N * 8;     //     48,000
  u32* listB = (u32*)(w + off);        off += 8192 * 4;
  u64* sorted = (u64*)(w + off);       off += 8192 * 8;
  float4* topbox = (float4*)(w + off); off += (size_t)PRE_NMS_N * 16;    //     96,000
  u64* mask = (u64*)(w + off);         off += (size_t)PRE_NMS_N * WPR * 8; // 4,512,000

  // 1. 3x3 conv + relu
  k_conv<<<dim3(118 * 4), dim3(256), 0, stream>>>(fm, Wr, br, rpn);
  // 2. heads + decode
  k_heads<<<dim3(NPIX), dim3(64), 0, stream>>>(rpn, Wsc, bsc, Wbb, bbb, img, fg, boxes);
  // 3. exact top-6000 radix select
  k_init<<<1, 256, 0, stream>>>(hist, ctl);
  for (int pass = 0; pass < 4; ++pass) {
    k_hist<<<128, 256, 0, stream>>>(fg, hist, ctl, pass);
    k_scan<<<1, 256, 0, stream>>>(hist, ctl);
  }
  k_compact<<<(NANCH + 255) / 256, 256, 0, stream>>>(fg, ctl, listA, listB);
  k_tiefix<<<1, 256, 0, stream>>>(ctl, listB, listA);
  // 4. sort the 6000 (desc score, asc index)
  k_sort<<<1, 1024, 0, stream>>>(listA, sorted);
  k_gather<<<(PRE_NMS_N + 255) / 256, 256, 0, stream>>>(sorted, boxes, topbox);
  // 5. NMS mask + greedy walk + emit 300
  k_mask<<<dim3(WPR, WPR), 64, 0, stream>>>(topbox, mask);
  k_nms<<<1, 64, 0, stream>>>(mask, (const float*)topbox, sorted, out);
}

// Round 2
// 1413.748 us; speedup vs baseline: 2.0230x; 2.0230x over previous
//
#include <hip/hip_runtime.h>
#include <hip/hip_bf16.h>

typedef unsigned int u32;
typedef unsigned long long u64;

#define H_FM 100
#define W_FM 150
#define CIN 1024
#define CMID 512
#define NPIX 15000          // H_FM * W_FM
#define NANCH 135000        // NPIX * 9
#define PRE_NMS_N 6000
#define POST_NMS_N 300
#define WPR 94              // ceil(6000/64) words per mask row

typedef __attribute__((ext_vector_type(8))) short short8;
typedef __attribute__((ext_vector_type(8))) __bf16 bf16x8;
typedef __attribute__((ext_vector_type(4))) float f32x4;

__device__ __forceinline__ u32 fkey(float f) {
  u32 u = __float_as_uint(f);
  return (u & 0x80000000u) ? ~u : (u | 0x80000000u);
}

__device__ __forceinline__ u64 shfl64(u64 v, int src) {
  u32 lo = (u32)__shfl((int)(u32)v, src, 64);
  u32 hi = (u32)__shfl((int)(u32)(v >> 32), src, 64);
  return ((u64)hi << 32) | (u64)lo;
}

// MFMA wrapper: tolerate either short8 or bf16x8 builtin operand signature.
struct FragArg {
  short8 v;
  __device__ operator short8() const { return v; }
  __device__ operator bf16x8() const { return __builtin_bit_cast(bf16x8, v); }
};
__device__ __forceinline__ f32x4 mfma16(short8 a, short8 b, f32x4 c) {
  return __builtin_amdgcn_mfma_f32_16x16x32_bf16(FragArg{a}, FragArg{b}, c, 0, 0, 0);
}

#define GLL(gp, lp) __builtin_amdgcn_global_load_lds(                        \
    (const __attribute__((address_space(1))) unsigned int*)(gp),             \
    (__attribute__((address_space(3))) unsigned int*)(lp), 16, 0, 0)

// ---------------------------------------------------------------------------
// bf16x3 split of feature map: fm (fp32 [pix][1024]) -> 3 bf16 planes.
// Also zeroes the 256-B zero-page used for conv halo handling.
// ---------------------------------------------------------------------------
__device__ __forceinline__ void split3(float f, unsigned short& a,
                                       unsigned short& b, unsigned short& c) {
  __hip_bfloat16 h0 = __float2bfloat16(f);
  float f0 = __bfloat162float(h0);
  float r1 = f - f0;
  __hip_bfloat16 h1 = __float2bfloat16(r1);
  float r2 = r1 - __bfloat162float(h1);
  __hip_bfloat16 h2 = __float2bfloat16(r2);
  a = *(unsigned short*)&h0;
  b = *(unsigned short*)&h1;
  c = *(unsigned short*)&h2;
}

__global__ __launch_bounds__(256) void k_split_fm(
    const float* __restrict__ src, unsigned short* __restrict__ d0,
    unsigned short* __restrict__ d1, unsigned short* __restrict__ d2,
    float* __restrict__ zp)
{
  if (blockIdx.x == 0 && threadIdx.x < 64) zp[threadIdx.x] = 0.f;
  const int n4 = NPIX * CIN / 4;
  for (int i = blockIdx.x * 256 + threadIdx.x; i < n4; i += gridDim.x * 256) {
    float4 v = ((const float4*)src)[i];
    float f[4] = {v.x, v.y, v.z, v.w};
    ushort4 o0, o1, o2;
    unsigned short* p0 = (unsigned short*)&o0;
    unsigned short* p1 = (unsigned short*)&o1;
    unsigned short* p2 = (unsigned short*)&o2;
    #pragma unroll
    for (int e = 0; e < 4; ++e) split3(f[e], p0[e], p1[e], p2[e]);
    ((ushort4*)d0)[i] = o0;
    ((ushort4*)d1)[i] = o1;
    ((ushort4*)d2)[i] = o2;
  }
}

// ---------------------------------------------------------------------------
// Split + transpose weights: W [9216 k][512 n] fp32 -> 3 bf16 planes [512 n][9216 k]
// ---------------------------------------------------------------------------
__global__ __launch_bounds__(256) void k_split_wt(
    const float* __restrict__ Wsrc, unsigned short* __restrict__ t0,
    unsigned short* __restrict__ t1, unsigned short* __restrict__ t2)
{
  __shared__ float tile[64][65];
  const int k0 = blockIdx.x * 64;   // 144 blocks
  const int n0 = blockIdx.y * 64;   // 8 blocks
  const int tid = threadIdx.x;
  const int lr = tid >> 4;          // 0..15
  const int lc = (tid & 15) * 4;
  #pragma unroll
  for (int rr = 0; rr < 64; rr += 16) {
    float4 v = *(const float4*)&Wsrc[(size_t)(k0 + lr + rr) * CMID + n0 + lc];
    tile[lr + rr][lc + 0] = v.x; tile[lr + rr][lc + 1] = v.y;
    tile[lr + rr][lc + 2] = v.z; tile[lr + rr][lc + 3] = v.w;
  }
  __syncthreads();
  const int n = tid >> 2;           // 0..63
  const int kk = (tid & 3) * 16;
  unsigned short b0[16], b1[16], b2[16];
  #pragma unroll
  for (int e = 0; e < 16; ++e) split3(tile[kk + e][n], b0[e], b1[e], b2[e]);
  size_t ob = ((size_t)(n0 + n) * 9216 + k0 + kk) >> 2;  // ushort4 index
  #pragma unroll
  for (int q = 0; q < 4; ++q) {
    ((ushort4*)t0)[ob + q] = *(ushort4*)&b0[q * 4];
    ((ushort4*)t1)[ob + q] = *(ushort4*)&b1[q * 4];
    ((ushort4*)t2)[ob + q] = *(ushort4*)&b2[q * 4];
  }
}

// ---------------------------------------------------------------------------
// MFMA conv: implicit GEMM M=15000,N=512,K=9216, bf16x3 split (6 products).
// 128x128 tile, BK=32, 4 waves of 64x64, mfma_f32_16x16x32_bf16.
// ---------------------------------------------------------------------------
__global__ __launch_bounds__(256, 2) void k_conv_mfma(
    const unsigned short* __restrict__ fm0, const unsigned short* __restrict__ fm1,
    const unsigned short* __restrict__ fm2, const unsigned short* __restrict__ wt0,
    const unsigned short* __restrict__ wt1, const unsigned short* __restrict__ wt2,
    const float* __restrict__ br, const float* __restrict__ zp,
    float* __restrict__ rpn)
{
  __shared__ char lds[49152];   // A: 3 splits x 8 KB; B at +24576 same

  const int tid = threadIdx.x;
  const int lane = tid & 63;
  const int w = tid >> 6;
  const int bn = (blockIdx.x & 3) * 128;
  const int bm = (blockIdx.x >> 2) * 128;
  const int wm = (w >> 1) * 64;
  const int wn = (w & 1) * 64;

  // fragment LDS offsets (chunk-invariant)
  unsigned aoff[3][4], boff[3][4];
  #pragma unroll
  for (int s = 0; s < 3; ++s)
    #pragma unroll
    for (int i = 0; i < 4; ++i) {
      aoff[s][i] = s * 8192 + (wm + i * 16 + (lane & 15)) * 64 + ((lane >> 4) << 4);
      boff[s][i] = 24576 + s * 8192 + (wn + i * 16 + (lane & 15)) * 64 + ((lane >> 4) << 4);
    }

  // staging geometry: this thread stages rows r0 (g=w) and r1 (g=w+4)
  const int subrow = lane >> 2;
  const unsigned colb = (lane & 3) << 4;
  const int mR0 = w * 16 + subrow;          // tile row for g=w pieces
  const int mR1 = (w + 4) * 16 + subrow;    // tile row for g=w+4 pieces
  char* ldsA0 = lds + w * 1024;
  char* ldsA1 = lds + (w + 4) * 1024;
  char* ldsB0 = lds + 24576 + w * 1024;
  char* ldsB1 = lds + 24576 + (w + 4) * 1024;
  const size_t rowB0 = (size_t)(bn + mR0) * 18432 + colb;
  const size_t rowB1 = (size_t)(bn + mR1) * 18432 + colb;
  const char* zpb = (const char*)zp + colb;

  f32x4 acc[4][4];
  #pragma unroll
  for (int i = 0; i < 4; ++i)
    #pragma unroll
    for (int j = 0; j < 4; ++j) acc[i][j] = (f32x4){0.f, 0.f, 0.f, 0.f};

  for (int seg = 0; seg < 9; ++seg) {
    const int dy = seg / 3 - 1, dx = seg % 3 - 1;
    size_t aO0 = 0, aO1 = 0;
    bool av0, av1;
    {
      int pm = bm + mR0;
      int y = pm / W_FM, x = pm - y * W_FM;
      int sy = y + dy, sx = x + dx;
      av0 = (pm < NPIX) && ((unsigned)sy < H_FM) && ((unsigned)sx < W_FM);
      aO0 = (size_t)(unsigned)(sy * W_FM + sx) * 2048 + colb;
    }
    {
      int pm = bm + mR1;
      int y = pm / W_FM, x = pm - y * W_FM;
      int sy = y + dy, sx = x + dx;
      av1 = (pm < NPIX) && ((unsigned)sy < H_FM) && ((unsigned)sx < W_FM);
      aO1 = (size_t)(unsigned)(sy * W_FM + sx) * 2048 + colb;
    }
    const size_t bS0 = rowB0 + (size_t)seg * 2048;
    const size_t bS1 = rowB1 + (size_t)seg * 2048;

    for (int chb = 0; chb < 2048; chb += 64) {   // 32 chunks of BK=32 (64 B)
      __syncthreads();
      {
        const char* g;
        g = av0 ? ((const char*)fm0 + aO0 + chb) : zpb; GLL(g, ldsA0);
        g = av1 ? ((const char*)fm0 + aO1 + chb) : zpb; GLL(g, ldsA1);
        g = av0 ? ((const char*)fm1 + aO0 + chb) : zpb; GLL(g, ldsA0 + 8192);
        g = av1 ? ((const char*)fm1 + aO1 + chb) : zpb; GLL(g, ldsA1 + 8192);
        g = av0 ? ((const char*)fm2 + aO0 + chb) : zpb; GLL(g, ldsA0 + 16384);
        g = av1 ? ((const char*)fm2 + aO1 + chb) : zpb; GLL(g, ldsA1 + 16384);
        GLL((const char*)wt0 + bS0 + chb, ldsB0);
        GLL((const char*)wt0 + bS1 + chb, ldsB1);
        GLL((const char*)wt1 + bS0 + chb, ldsB0 + 8192);
        GLL((const char*)wt1 + bS1 + chb, ldsB1 + 8192);
        GLL((const char*)wt2 + bS0 + chb, ldsB0 + 16384);
        GLL((const char*)wt2 + bS1 + chb, ldsB1 + 16384);
      }
      __syncthreads();

      short8 B0[4], B1[4], B2[4];
      #pragma unroll
      for (int j = 0; j < 4; ++j) {
        B0[j] = *(const short8*)(lds + boff[0][j]);
        B1[j] = *(const short8*)(lds + boff[1][j]);
        B2[j] = *(const short8*)(lds + boff[2][j]);
      }
      #pragma unroll
      for (int i = 0; i < 4; ++i) {
        short8 A0 = *(const short8*)(lds + aoff[0][i]);
        short8 A1 = *(const short8*)(lds + aoff[1][i]);
        short8 A2 = *(const short8*)(lds + aoff[2][i]);
        #pragma unroll
        for (int j = 0; j < 4; ++j) {
          f32x4 c = acc[i][j];
          c = mfma16(A0, B0[j], c);
          c = mfma16(A0, B1[j], c);
          c = mfma16(A1, B0[j], c);
          c = mfma16(A1, B1[j], c);
          c = mfma16(A0, B2[j], c);
          c = mfma16(A2, B0[j], c);
          acc[i][j] = c;
        }
      }
    }
  }

  // epilogue: bias + relu + store (C/D: row=(lane>>4)*4+reg, col=lane&15)
  #pragma unroll
  for (int i = 0; i < 4; ++i) {
    const int mbase = bm + wm + i * 16 + ((lane >> 4) << 2);
    #pragma unroll
    for (int j = 0; j < 4; ++j) {
      const int n = bn + wn + j * 16 + (lane & 15);
      const float bias = br[n];
      #pragma unroll
      for (int r = 0; r < 4; ++r) {
        const int m = mbase + r;
        if (m < NPIX) rpn[(size_t)m * CMID + n] = fmaxf(acc[i][j][r] + bias, 0.f);
      }
    }
  }
}

// ---------------------------------------------------------------------------
// Fallback fp32 conv (used only if workspace too small for the MFMA path).
// ---------------------------------------------------------------------------
__global__ __launch_bounds__(256) void k_conv(
    const float* __restrict__ fm, const float* __restrict__ Wr,
    const float* __restrict__ br, float* __restrict__ rpn)
{
  __shared__ float As[16][132];
  __shared__ float Bs[16][128];

  const int tid = threadIdx.x;
  const int ntile = blockIdx.x & 3;
  const int mtile = blockIdx.x >> 2;
  const int bm = mtile * 128, bn = ntile * 128;

  const int a_kg = tid & 3;
  const int a_r  = tid >> 2;
  const int m0 = bm + a_r, m1 = m0 + 64;
  const int y0 = m0 / W_FM, x0 = m0 % W_FM;
  const int y1 = m1 / W_FM, x1 = m1 % W_FM;
  const bool mv0 = m0 < NPIX, mv1 = m1 < NPIX;

  const int b_n4 = (tid & 31) << 2;
  const int b_k  = tid >> 5;
  const int tc = tid & 15, tr = tid >> 4;

  float acc[8][8];
  #pragma unroll
  for (int i = 0; i < 8; ++i)
    #pragma unroll
    for (int j = 0; j < 8; ++j) acc[i][j] = 0.f;

  const float4 z4 = make_float4(0.f, 0.f, 0.f, 0.f);

  for (int seg = 0; seg < 9; ++seg) {
    const int dy = seg / 3 - 1, dx = seg % 3 - 1;
    const int iy0 = y0 + dy, ix0 = x0 + dx;
    const int iy1 = y1 + dy, ix1 = x1 + dx;
    const bool v0 = mv0 && (unsigned)iy0 < H_FM && (unsigned)ix0 < W_FM;
    const bool v1 = mv1 && (unsigned)iy1 < H_FM && (unsigned)ix1 < W_FM;
    const float* pa0 = fm + (((iy0 * W_FM + ix0) << 10) + (a_kg << 2));
    const float* pa1 = fm + (((iy1 * W_FM + ix1) << 10) + (a_kg << 2));
    const float* pb  = Wr + ((size_t)(seg * CIN) * CMID) + bn + b_n4;

    for (int kc = 0; kc < CIN; kc += 16) {
      float4 av0 = v0 ? *(const float4*)(pa0 + kc) : z4;
      float4 av1 = v1 ? *(const float4*)(pa1 + kc) : z4;
      float4 bv0 = *(const float4*)(pb + (size_t)(kc + b_k) * CMID);
      float4 bv1 = *(const float4*)(pb + (size_t)(kc + b_k + 8) * CMID);

      __syncthreads();
      const int ka = a_kg << 2;
      As[ka + 0][a_r] = av0.x; As[ka + 1][a_r] = av0.y;
      As[ka + 2][a_r] = av0.z; As[ka + 3][a_r] = av0.w;
      As[ka + 0][a_r + 64] = av1.x; As[ka + 1][a_r + 64] = av1.y;
      As[ka + 2][a_r + 64] = av1.z; As[ka + 3][a_r + 64] = av1.w;
      *(float4*)&Bs[b_k][b_n4]     = bv0;
      *(float4*)&Bs[b_k + 8][b_n4] = bv1;
      __syncthreads();

      #pragma unroll
      for (int kk = 0; kk < 16; ++kk) {
        float a8[8], b8[8];
        *(float4*)&a8[0] = *(const float4*)&As[kk][tr * 8];
        *(float4*)&a8[4] = *(const float4*)&As[kk][tr * 8 + 4];
        *(float4*)&b8[0] = *(const float4*)&Bs[kk][tc * 8];
        *(float4*)&b8[4] = *(const float4*)&Bs[kk][tc * 8 + 4];
        #pragma unroll
        for (int i = 0; i < 8; ++i)
          #pragma unroll
          for (int j = 0; j < 8; ++j)
            acc[i][j] = fmaf(a8[i], b8[j], acc[i][j]);
      }
    }
  }

  float4 bias0 = *(const float4*)(br + bn + tc * 8);
  float4 bias1 = *(const float4*)(br + bn + tc * 8 + 4);
  #pragma unroll
  for (int i = 0; i < 8; ++i) {
    int m = bm + tr * 8 + i;
    if (m < NPIX) {
      float* op = rpn + (size_t)m * CMID + bn + tc * 8;
      float4 o0, o1;
      o0.x = fmaxf(acc[i][0] + bias0.x, 0.f);
      o0.y = fmaxf(acc[i][1] + bias0.y, 0.f);
      o0.z = fmaxf(acc[i][2] + bias0.z, 0.f);
      o0.w = fmaxf(acc[i][3] + bias0.w, 0.f);
      o1.x = fmaxf(acc[i][4] + bias1.x, 0.f);
      o1.y = fmaxf(acc[i][5] + bias1.y, 0.f);
      o1.z = fmaxf(acc[i][6] + bias1.z, 0.f);
      o1.w = fmaxf(acc[i][7] + bias1.w, 0.f);
      *(float4*)op = o0;
      *(float4*)(op + 4) = o1;
    }
  }
}

// ---------------------------------------------------------------------------
// 1x1 heads + softmax + anchor decode + clip + min-size filter.
// ---------------------------------------------------------------------------
__global__ __launch_bounds__(64) void k_heads(
    const float* __restrict__ rpn,
    const float* __restrict__ Ws, const float* __restrict__ bs,
    const float* __restrict__ Wb, const float* __restrict__ bb,
    const int* __restrict__ img,
    float* __restrict__ fg, float4* __restrict__ boxes)
{
  __shared__ float r[512];
  __shared__ float vals[54];
  const int p = blockIdx.x, lane = threadIdx.x;
  const float* rp = rpn + (size_t)p * CMID;
  *(float4*)&r[lane * 8]     = *(const float4*)(rp + lane * 8);
  *(float4*)&r[lane * 8 + 4] = *(const float4*)(rp + lane * 8 + 4);
  __syncthreads();

  if (lane < 54) {
    const float* wp;
    int stride;
    float acc;
    if (lane < 18) { wp = Ws + lane; stride = 18; acc = bs[lane]; }
    else           { wp = Wb + (lane - 18); stride = 36; acc = bb[lane - 18]; }
    #pragma unroll 8
    for (int c = 0; c < 512; ++c) acc = fmaf(r[c], wp[c * stride], acc);
    vals[lane] = acc;
  }
  __syncthreads();

  if (lane < 9) {
    const int a = lane;
    const float AW[9] = {184.f, 368.f, 736.f, 128.f, 256.f, 512.f,  88.f, 176.f, 352.f};
    const float AH[9] = { 96.f, 192.f, 384.f, 128.f, 256.f, 512.f, 176.f, 352.f, 704.f};
    const int y = p / W_FM, x = p % W_FM;

    float c0 = vals[2 * a], c1 = vals[2 * a + 1];
    float score = 1.f / (1.f + expf(c0 - c1));

    float dxv = vals[18 + 4 * a + 0];
    float dyv = vals[18 + 4 * a + 1];
    float dwv = vals[18 + 4 * a + 2];
    float dhv = vals[18 + 4 * a + 3];

    float aw = AW[a], ah = AH[a];
    float acx = (float)(x * 16 + 8);
    float acy = (float)(y * 16 + 8);
    float pcx = dxv * aw + acx;
    float pcy = dyv * ah + acy;
    float pw = expf(dwv) * aw;
    float ph = expf(dhv) * ah;

    float imh1 = (float)img[0] - 1.f;
    float imw1 = (float)img[1] - 1.f;
    float b0 = fminf(fmaxf(pcx - 0.5f * pw, 0.f), imw1);
    float b1 = fminf(fmaxf(pcy - 0.5f * ph, 0.f), imh1);
    float b2 = fminf(fmaxf(pcx + 0.5f * pw, 0.f), imw1);
    float b3 = fminf(fmaxf(pcy + 0.5f * ph, 0.f), imh1);

    float bw = b2 - b0 + 1.f, bh = b3 - b1 + 1.f;
    if (!(bw >= 16.f && bh >= 16.f)) score = -1e9f;

    int gi = p * 9 + a;
    fg[gi] = score;
    boxes[gi] = make_float4(b0, b1, b2, b3);
  }
}

// ---------------------------------------------------------------------------
// Radix-select (exact top-6000 threshold) machinery.
// ---------------------------------------------------------------------------
__global__ void k_init(u32* __restrict__ hist, u32* __restrict__ ctl) {
  hist[threadIdx.x] = 0;
  if (threadIdx.x == 0) { ctl[0] = 0; ctl[1] = PRE_NMS_N; ctl[2] = 0; ctl[3] = 0; }
}

__global__ __launch_bounds__(256) void k_hist(
    const float* __restrict__ fg, u32* __restrict__ hist,
    const u32* __restrict__ ctl, int pass)
{
  __shared__ u32 h[256];
  h[threadIdx.x] = 0;
  __syncthreads();
  const int shift = 24 - 8 * pass;
  const u32 prefix = ctl[0];
  for (int i = blockIdx.x * 256 + threadIdx.x; i < NANCH; i += 128 * 256) {
    u32 key = fkey(fg[i]);
    bool match = (pass == 0) || ((key >> (shift + 8)) == prefix);
    if (match) atomicAdd(&h[(key >> shift) & 255], 1u);
  }
  __syncthreads();
  u32 c = h[threadIdx.x];
  if (c) atomicAdd(&hist[threadIdx.x], c);
}

__global__ void k_scan(u32* __restrict__ hist, u32* __restrict__ ctl) {
  if (threadIdx.x == 0) {
    u32 kneed = ctl[1];
    u32 cum = 0;
    int d = 0;
    for (int dd = 255; dd >= 0; --dd) {
      u32 c = hist[dd];
      if (cum + c >= kneed) { d = dd; break; }
      cum += c;
    }
    ctl[0] = (ctl[0] << 8) | (u32)d;
    ctl[1] = kneed - cum;
  }
  __syncthreads();
  hist[threadIdx.x] = 0;
}

__global__ __launch_bounds__(256) void k_compact(
    const float* __restrict__ fg, u32* __restrict__ ctl,
    u64* __restrict__ listA, u32* __restrict__ listB)
{
  int i = blockIdx.x * 256 + threadIdx.x;
  if (i >= NANCH) return;
  u32 T = ctl[0];
  u32 key = fkey(fg[i]);
  if (key > T) {
    u32 slot = atomicAdd(&ctl[2], 1u);
    listA[slot] = ((u64)key << 32) | (u64)(0xFFFFFFFFu - (u32)i);
  } else if (key == T) {
    u32 slot = atomicAdd(&ctl[3], 1u);
    if (slot < 8192) listB[slot] = (u32)i;
  }
}

__global__ __launch_bounds__(256) void k_tiefix(
    u32* __restrict__ ctl, const u32* __restrict__ listB, u64* __restrict__ listA)
{
  __shared__ u32 s[8192];
  const int tid = threadIdx.x;
  const u32 kneed = ctl[1];
  const u32 base = ctl[2];
  const u32 cntB = min(ctl[3], 8192u);
  const u32 T = ctl[0];
  if (kneed == 0) return;
  if (cntB == kneed) {
    for (u32 t = tid; t < kneed; t += 256)
      listA[base + t] = ((u64)T << 32) | (u64)(0xFFFFFFFFu - listB[t]);
    return;
  }
  u32 n2 = 1;
  while (n2 < cntB) n2 <<= 1;
  for (u32 i = tid; i < n2; i += 256) s[i] = (i < cntB) ? listB[i] : 0xFFFFFFFFu;
  __syncthreads();
  for (u32 k = 2; k <= n2; k <<= 1) {
    for (u32 j = k >> 1; j > 0; j >>= 1) {
      for (u32 i = tid; i < n2; i += 256) {
        u32 ixj = i ^ j;
        if (ixj > i) {
          u32 a = s[i], b = s[ixj];
          bool up = ((i & k) == 0);
          if ((a > b) == up) { s[i] = b; s[ixj] = a; }
        }
      }
      __syncthreads();
    }
  }
  for (u32 t = tid; t < kneed; t += 256)
    listA[base + t] = ((u64)T << 32) | (u64)(0xFFFFFFFFu - s[t]);
}

__global__ __launch_bounds__(1024) void k_sort(
    const u64* __restrict__ listA, u64* __restrict__ sorted)
{
  __shared__ u64 s[8192];
  const int tid = threadIdx.x;
  for (int i = tid; i < 8192; i += 1024) s[i] = (i < PRE_NMS_N) ? listA[i] : 0ull;
  __syncthreads();
  for (int k = 2; k <= 8192; k <<= 1) {
    for (int j = k >> 1; j > 0; j >>= 1) {
      for (int i = tid; i < 8192; i += 1024) {
        int ixj = i ^ j;
        if (ixj > i) {
          u64 a = s[i], b = s[ixj];
          bool up = ((i & k) == 0);
          if ((a < b) == up) { s[i] = b; s[ixj] = a; }
        }
      }
      __syncthreads();
    }
  }
  for (int i = tid; i < 8192; i += 1024) sorted[i] = s[i];
}

__global__ __launch_bounds__(256) void k_gather(
    const u64* __restrict__ sorted, const float4* __restrict__ boxes,
    float4* __restrict__ tb)
{
  int t = blockIdx.x * 256 + threadIdx.x;
  if (t >= PRE_NMS_N) return;
  u64 p = sorted[t];
  u32 idx = 0xFFFFFFFFu - (u32)(p & 0xFFFFFFFFull);
  tb[t] = boxes[idx];
}

__global__ __launch_bounds__(64) void k_mask(
    const float4* __restrict__ tb, u64* __restrict__ mask)
{
  __shared__ float4 cb[64];
  const int bj = blockIdx.x, bi = blockIdx.y, t = threadIdx.x;
  const int j0 = bj * 64;
  const int jn = min(64, PRE_NMS_N - j0);
  if (t < jn) cb[t] = tb[j0 + t];
  __syncthreads();
  const int i = bi * 64 + t;
  if (i >= PRE_NMS_N) return;
  const float4 b = tb[i];
  const float ai = (b.z - b.x + 1.f) * (b.w - b.y + 1.f);
  u64 bits = 0;
  for (int tt = 0; tt < jn; ++tt) {
    int j = j0 + tt;
    if (j <= i) continue;
    float4 c = cb[tt];
    float iw = fminf(b.z, c.z) - fmaxf(b.x, c.x) + 1.f;
    float ih = fminf(b.w, c.w) - fmaxf(b.y, c.y) + 1.f;
    float inter = fmaxf(iw, 0.f) * fmaxf(ih, 0.f);
    float aj = (c.z - c.x + 1.f) * (c.w - c.y + 1.f);
    float iou = inter / (ai + aj - inter);
    if (iou > 0.7f) bits |= (1ull << tt);
  }
  mask[(size_t)i * WPR + bj] = bits;
}

__global__ __launch_bounds__(64) void k_nms(
    const u64* __restrict__ mask, const float* __restrict__ tb,
    const u64* __restrict__ sorted, float* __restrict__ out)
{
  const int lane = threadIdx.x;
  u64 r0 = 0, r1 = 0;
  int kept = 0;
  const u32 kcut = fkey(-1e8f);
  for (int i = 0; i < PRE_NMS_N; ++i) {
    const int w = i >> 6, b = i & 63;
    u64 v0 = shfl64(r0, w & 63);
    u64 v1 = shfl64(r1, w & 63);
    u64 word = (w < 64) ? v0 : v1;
    if (!((word >> b) & 1ull)) {
      u32 key = (u32)(sorted[i] >> 32);
      if (key <= kcut) break;
      if (lane < 4) out[kept * 4 + lane] = tb[i * 4 + lane];
      ++kept;
      if (kept >= POST_NMS_N) break;
      const u64* row = mask + (size_t)i * WPR;
      r0 |= row[lane];
      if (lane < WPR - 64) r1 |= row[64 + lane];
    }
  }
  for (int j = kept * 4 + lane; j < POST_NMS_N * 4; j += 64) out[j] = 0.f;
}

// ---------------------------------------------------------------------------
extern "C" void kernel_launch(void* const* d_in, const int* in_sizes, int n_in,
                              void* d_out, int out_size, void* d_ws, size_t ws_size,
                              hipStream_t stream) {
  const float* fm  = (const float*)d_in[0];
  const float* Wr  = (const float*)d_in[1];
  const float* br  = (const float*)d_in[2];
  const float* Wsc = (const float*)d_in[3];
  const float* bsc = (const float*)d_in[4];
  const float* Wbb = (const float*)d_in[5];
  const float* bbb = (const float*)d_in[6];
  const int*   img = (const int*)d_in[7];
  float* out = (float*)d_out;

  char* w = (char*)d_ws;
  size_t off = 0;
  auto alloc = [&](size_t bytes) {
    size_t p = off;
    off = (off + bytes + 255) & ~(size_t)255;
    return p;
  };
  float* rpn    = (float*)(w + alloc((size_t)NPIX * CMID * 4));
  float* fg     = (float*)(w + alloc((size_t)NANCH * 4));
  float4* boxes = (float4*)(w + alloc((size_t)NANCH * 16));
  u32* hist     = (u32*)(w + alloc(1024));
  u32* ctl      = (u32*)(w + alloc(64));
  u64* listA    = (u64*)(w + alloc((size_t)PRE_NMS_N * 8));
  u32* listB    = (u32*)(w + alloc(8192 * 4));
  u64* sorted   = (u64*)(w + alloc(8192 * 8));
  float4* topbox= (float4*)(w + alloc((size_t)PRE_NMS_N * 16));
  u64* mask     = (u64*)(w + alloc((size_t)PRE_NMS_N * WPR * 8));
  float* zp     = (float*)(w + alloc(256));
  size_t fb = (size_t)NPIX * CIN * 2;     // 30,720,000 per split plane
  size_t wb = (size_t)9216 * CMID * 2;    //  9,437,184 per split plane
  unsigned short* fm0 = (unsigned short*)(w + alloc(fb));
  unsigned short* fm1 = (unsigned short*)(w + alloc(fb));
  unsigned short* fm2 = (unsigned short*)(w + alloc(fb));
  unsigned short* wt0 = (unsigned short*)(w + alloc(wb));
  unsigned short* wt1 = (unsigned short*)(w + alloc(wb));
  unsigned short* wt2 = (unsigned short*)(w + alloc(wb));
  const bool use_mfma = ws_size >= off;

  // 1. conv
  if (use_mfma) {
    k_split_fm<<<dim3(1024), dim3(256), 0, stream>>>(fm, fm0, fm1, fm2, zp);
    k_split_wt<<<dim3(144, 8), dim3(256), 0, stream>>>(Wr, wt0, wt1, wt2);
    k_conv_mfma<<<dim3(118 * 4), dim3(256), 0, stream>>>(
        fm0, fm1, fm2, wt0, wt1, wt2, br, zp, rpn);
  } else {
    k_conv<<<dim3(118 * 4), dim3(256), 0, stream>>>(fm, Wr, br, rpn);
  }
  // 2. heads + decode
  k_heads<<<dim3(NPIX), dim3(64), 0, stream>>>(rpn, Wsc, bsc, Wbb, bbb, img, fg, boxes);
  // 3. exact top-6000 radix select
  k_init<<<1, 256, 0, stream>>>(hist, ctl);
  for (int pass = 0; pass < 4; ++pass) {
    k_hist<<<128, 256, 0, stream>>>(fg, hist, ctl, pass);
    k_scan<<<1, 256, 0, stream>>>(hist, ctl);
  }
  k_compact<<<(NANCH + 255) / 256, 256, 0, stream>>>(fg, ctl, listA, listB);
  k_tiefix<<<1, 256, 0, stream>>>(ctl, listB, listA);
  // 4. sort the 6000 (desc score, asc index)
  k_sort<<<1, 1024, 0, stream>>>(listA, sorted);
  k_gather<<<(PRE_NMS_N + 255) / 256, 256, 0, stream>>>(sorted, boxes, topbox);
  // 5. NMS mask + greedy walk + emit 300
  k_mask<<<dim3(WPR, WPR), 64, 0, stream>>>(topbox, mask);
  k_nms<<<1, 64, 0, stream>>>(mask, (const float*)topbox, sorted, out);
}